// Round 10
// baseline (253.025 us; speedup 1.0000x reference)
//
#include <hip/hip_runtime.h>
#include <cstdint>
#include <cstddef>

#define NH 16
#define DH 64
#define SEQ 2048
#define DM 1024

typedef __attribute__((ext_vector_type(8))) short short8;
typedef __attribute__((ext_vector_type(4))) float f32x4;

__device__ __forceinline__ unsigned short f2bf(float f) {
  unsigned u = __builtin_bit_cast(unsigned, f);
  u += 0x7fffu + ((u >> 16) & 1u);
  return (unsigned short)(u >> 16);
}

__device__ __forceinline__ void gld_lds16(const void* g, void* l) {
  __builtin_amdgcn_global_load_lds((const __attribute__((address_space(1))) void*)g,
                                   (__attribute__((address_space(3))) void*)l,
                                   16, 0, 0);
}

// ---------------- one-launch fp32 -> bf16 cast of x + all 4 weights ----------------
__global__ __launch_bounds__(256) void cast_all_kernel(const float* __restrict__ x,
                                                       const float* __restrict__ wq,
                                                       const float* __restrict__ wk,
                                                       const float* __restrict__ wv,
                                                       const float* __restrict__ wo,
                                                       unsigned short* __restrict__ xb,
                                                       unsigned short* __restrict__ wqkvb,
                                                       unsigned short* __restrict__ wob) {
  const int bid = blockIdx.x;
  const float* in;
  unsigned short* out;
  int i;
  if (bid < 8192) {
    in = x; out = xb; i = bid * 256 + threadIdx.x;
  } else {
    const int w = (bid - 8192) >> 10;
    i = ((bid - 8192) & 1023) * 256 + threadIdx.x;
    in = (w == 0) ? wq : (w == 1) ? wk : (w == 2) ? wv : wo;
    out = (w < 3) ? (wqkvb + (size_t)w * 1048576) : wob;
  }
  const float4 v = ((const float4*)in)[i];
  ushort4 o;
  o.x = f2bf(v.x); o.y = f2bf(v.y); o.z = f2bf(v.z); o.w = f2bf(v.w);
  ((ushort4*)out)[i] = o;
}

// ============ fused QKV GEMM: 256x256 tile, BK=64, 4-phase K-tiles (round-3 proven) ==
__global__ __launch_bounds__(512, 2) void gemm_qkv256(const unsigned short* __restrict__ A,
                                                      const unsigned short* __restrict__ W,
                                                      unsigned short* __restrict__ qb,
                                                      unsigned short* __restrict__ kb,
                                                      unsigned short* __restrict__ vtb) {
  extern __shared__ __align__(16) char sm[];   // [0,64K) = A par0/par1; [64K,128K) = B

  const int t = threadIdx.x;
  const int lane = t & 63;
  const int wave = t >> 6;            // 0..7
  const int quad = lane >> 4;
  const int l16 = lane & 15;
  const int wr = wave >> 2;           // 0,1  -> rows wr*128
  const int wc = wave & 3;            // 0..3 -> cols wc*64

  const int bid = blockIdx.x;         // 0..383
  const int xcd = bid & 7;
  const int idx = bid >> 3;           // 0..47
  const int bm = (xcd * 4 + idx / 12) * 256;
  const int bn = (idx % 12) * 256;
  const int sel = bn >> 10;
  const int bnl = bn & 1023;

  f32x4 acc[8][4];
#pragma unroll
  for (int i = 0; i < 8; ++i)
#pragma unroll
    for (int j = 0; j < 4; ++j) acc[i][j] = {0.0f, 0.0f, 0.0f, 0.0f};

  const int r0s = t >> 3;                         // 0..63
  const int g0 = (((t & 7) ^ (r0s & 7)) * 8);
  const unsigned short* aS0 = A + (size_t)(bm + r0s) * DM + g0;
  const unsigned short* aS1 = A + (size_t)(bm + 64 + r0s) * DM + g0;
  const unsigned short* bS0 = W + (size_t)(bn + r0s) * DM + g0;
  const unsigned short* bS1 = W + (size_t)(bn + 64 + r0s) * DM + g0;
  const int t16 = t * 16;

  const int aswz = (quad ^ (l16 & 7)) * 16;
  const int aRd0 = (wr * 128 + l16) * 128 + aswz;
  const int aRd1 = aRd0 ^ 64;
  const int bRd0 = 65536 + (wc * 64 + l16) * 128 + aswz;
  const int bRd1 = bRd0 ^ 64;

#define ST_A(U, TK, PAR)                                                                   \
  {                                                                                        \
    gld_lds16(aS0 + (size_t)(U) * 131072 + (TK) * 64, sm + (PAR) * 32768 + (U) * 16384 + t16); \
    gld_lds16(aS1 + (size_t)(U) * 131072 + (TK) * 64,                                      \
              sm + (PAR) * 32768 + (U) * 16384 + 8192 + t16);                              \
  }
#define ST_B(U, TK, PAR)                                                                   \
  {                                                                                        \
    gld_lds16(bS0 + (size_t)(U) * 131072 + (TK) * 64,                                      \
              sm + 65536 + (PAR) * 32768 + (U) * 16384 + t16);                             \
    gld_lds16(bS1 + (size_t)(U) * 131072 + (TK) * 64,                                      \
              sm + 65536 + (PAR) * 32768 + (U) * 16384 + 8192 + t16);                      \
  }

#define MM(AF, BF, IB, JB)                                                                 \
  _Pragma("unroll")                                                                        \
  for (int i = 0; i < 4; ++i)                                                              \
    _Pragma("unroll")                                                                      \
    for (int j = 0; j < 2; ++j) {                                                          \
      acc[(IB) + i][(JB) + j] = __builtin_amdgcn_mfma_f32_16x16x32_bf16(                   \
          AF[i][0], BF[j][0], acc[(IB) + i][(JB) + j], 0, 0, 0);                           \
      acc[(IB) + i][(JB) + j] = __builtin_amdgcn_mfma_f32_16x16x32_bf16(                   \
          AF[i][1], BF[j][1], acc[(IB) + i][(JB) + j], 0, 0, 0);                           \
    }

#define TILE(T, PAR, SB, SA, VM)                                                           \
  {                                                                                        \
    short8 af0[4][2], af1[4][2], bf0[2][2], bf1[2][2];                                     \
    _Pragma("unroll")                                                                      \
    for (int i = 0; i < 4; ++i) {                                                          \
      af0[i][0] = *(const short8*)(sm + (PAR) * 32768 + i * 2048 + aRd0);                  \
      af0[i][1] = *(const short8*)(sm + (PAR) * 32768 + i * 2048 + aRd1);                  \
    }                                                                                      \
    _Pragma("unroll")                                                                      \
    for (int j = 0; j < 2; ++j) {                                                          \
      bf0[j][0] = *(const short8*)(sm + (PAR) * 32768 + j * 2048 + bRd0);                  \
      bf0[j][1] = *(const short8*)(sm + (PAR) * 32768 + j * 2048 + bRd1);                  \
    }                                                                                      \
    if (SB) ST_B(0, (T) + 1, (PAR) ^ 1);                                                   \
    asm volatile("" ::: "memory");                                                         \
    __builtin_amdgcn_s_barrier();                                                          \
    asm volatile("s_waitcnt lgkmcnt(0)" ::: "memory");                                     \
    __builtin_amdgcn_s_setprio(1);                                                         \
    MM(af0, bf0, 0, 0);                                                                    \
    __builtin_amdgcn_s_setprio(0);                                                         \
    asm volatile("" ::: "memory");                                                         \
    __builtin_amdgcn_s_barrier();                                                          \
    _Pragma("unroll")                                                                      \
    for (int i = 0; i < 4; ++i) {                                                          \
      af1[i][0] = *(const short8*)(sm + (PAR) * 32768 + 8192 + i * 2048 + aRd0);           \
      af1[i][1] = *(const short8*)(sm + (PAR) * 32768 + 8192 + i * 2048 + aRd1);           \
    }                                                                                      \
    if (SB) ST_B(1, (T) + 1, (PAR) ^ 1);                                                   \
    asm volatile("" ::: "memory");                                                         \
    __builtin_amdgcn_s_barrier();                                                          \
    asm volatile("s_waitcnt lgkmcnt(0)" ::: "memory");                                     \
    __builtin_amdgcn_s_setprio(1);                                                         \
    MM(af1, bf0, 4, 0);                                                                    \
    __builtin_amdgcn_s_setprio(0);                                                         \
    asm volatile("" ::: "memory");                                                         \
    __builtin_amdgcn_s_barrier();                                                          \
    _Pragma("unroll")                                                                      \
    for (int j = 0; j < 2; ++j) {                                                          \
      bf1[j][0] = *(const short8*)(sm + (PAR) * 32768 + (2 + j) * 2048 + bRd0);            \
      bf1[j][1] = *(const short8*)(sm + (PAR) * 32768 + (2 + j) * 2048 + bRd1);            \
    }                                                                                      \
    if (SA) ST_A(0, (T) + 2, (PAR));                                                       \
    asm volatile("" ::: "memory");                                                         \
    __builtin_amdgcn_s_barrier();                                                          \
    asm volatile("s_waitcnt lgkmcnt(0)" ::: "memory");                                     \
    __builtin_amdgcn_s_setprio(1);                                                         \
    MM(af1, bf1, 4, 2);                                                                    \
    __builtin_amdgcn_s_setprio(0);                                                         \
    asm volatile("" ::: "memory");                                                         \
    __builtin_amdgcn_s_barrier();                                                          \
    if (SA) ST_A(1, (T) + 2, (PAR));                                                       \
    asm volatile("" ::: "memory");                                                         \
    __builtin_amdgcn_s_barrier();                                                          \
    __builtin_amdgcn_s_setprio(1);                                                         \
    MM(af0, bf1, 0, 2);                                                                    \
    __builtin_amdgcn_s_setprio(0);                                                         \
    if ((VM) == 4) asm volatile("s_waitcnt vmcnt(4)" ::: "memory");                        \
    else if ((VM) == 0) asm volatile("s_waitcnt vmcnt(0)" ::: "memory");                   \
    asm volatile("" ::: "memory");                                                         \
    __builtin_amdgcn_s_barrier();                                                          \
  }

  ST_A(0, 0, 0); ST_A(1, 0, 0);
  ST_B(0, 0, 0); ST_B(1, 0, 0);
  ST_A(0, 1, 1); ST_A(1, 1, 1);
  asm volatile("s_waitcnt vmcnt(4)" ::: "memory");
  __builtin_amdgcn_s_barrier();

#pragma unroll 1
  for (int tp = 0; tp < 7; ++tp) {      // tiles 0..13
    const int T0 = tp * 2;
    TILE(T0, 0, 1, 1, 4)
    TILE(T0 + 1, 1, 1, 1, 4)
  }
  TILE(14, 0, 1, 0, 0)
  TILE(15, 1, 0, 0, -1)

#undef TILE
#undef MM
#undef ST_A
#undef ST_B

  if (sel == 2) {
    // ---- V epilogue: LDS transpose -> coalesced dwordx4 stores along s ----
    __syncthreads();
#pragma unroll
    for (int i = 0; i < 8; ++i) {
#pragma unroll
      for (int j = 0; j < 4; ++j) {
        const int n = wc * 64 + j * 16 + l16;
        const int nrow = n * 512;
        const int cswz = (n & 15) << 5;
        const int mb = wr * 128 + i * 16 + quad * 4;
#pragma unroll
        for (int rp = 0; rp < 2; ++rp) {
          const unsigned lo = f2bf(acc[i][j][rp * 2]);
          const unsigned hi = f2bf(acc[i][j][rp * 2 + 1]);
          const int m0 = mb + rp * 2;
          *(unsigned*)(sm + nrow + ((2 * m0) ^ cswz)) = lo | (hi << 16);
        }
      }
    }
    __syncthreads();
    const int mc = t & 31;
    const int nb0 = t >> 5;
    const int bb = bm >> 11;
    const int sbase = (bm & 2047) + mc * 8;
#pragma unroll
    for (int c = 0; c < 16; ++c) {
      const int n = nb0 + c * 16;
      const f32x4 v = *(const f32x4*)(sm + n * 512 + ((mc * 16) ^ ((n & 15) << 5)));
      const int gcol = bnl + n;
      const int h = gcol >> 6, d = gcol & 63;
      *(f32x4*)(vtb + ((size_t)((bb * NH + h) * DH + d)) * SEQ + sbase) = v;
    }
  } else {
#pragma unroll
    for (int i = 0; i < 8; ++i) {
#pragma unroll
      for (int j = 0; j < 4; ++j) {
#pragma unroll
        for (int r = 0; r < 4; ++r) {
          const int m = bm + wr * 128 + i * 16 + quad * 4 + r;
          const int n = bnl + wc * 64 + j * 16 + l16;
          const float v = acc[i][j][r];
          if (sel == 0) {
            // q pre-scaled by (1/sqrt(Dh)) * log2(e) = 0.18033688 so attn can use
            // exp2f (bare v_exp_f32 via COMPILER lowering — the R7 failure was
            // inline-asm hazard loss, not the math; builtin path is hazard-safe).
            qb[(size_t)m * DM + n] = f2bf(v * 0.18033688f);
          } else {
            kb[(size_t)m * DM + n] = f2bf(v);
          }
        }
      }
    }
  }
}

// ============ O-projection GEMM, BK=32: fp32 out, XCD-aware remap (round-3) ========
__global__ __launch_bounds__(256, 4) void gemm_o(const unsigned short* __restrict__ A,
                                                 const unsigned short* __restrict__ B,
                                                 float* __restrict__ C) {
  __shared__ __align__(16) unsigned short As[128 * 32];
  __shared__ __align__(16) unsigned short Bs[128 * 32];
  const int t = threadIdx.x;
  const int lane = t & 63;
  const int wave = t >> 6;
  const int quad = lane >> 4;
  const int l16 = lane & 15;
  const int wm = (wave >> 1) * 64;
  const int wn = (wave & 1) * 64;

  const int lid = blockIdx.x + 8 * blockIdx.y;   // 0..511
  const int xcd = lid & 7;
  const int idx = lid >> 3;                      // 0..63
  const int bm = (xcd * 8 + idx / 8) * 128;
  const int bn = (idx % 8) * 128;

  f32x4 acc[4][4];
#pragma unroll
  for (int i = 0; i < 4; ++i)
#pragma unroll
    for (int j = 0; j < 4; ++j) acc[i][j] = {0.0f, 0.0f, 0.0f, 0.0f};

  const int srow = t >> 2;
  const int sc = (t & 3) ^ ((srow >> 1) & 3);
  const unsigned short* Ag1 = A + (size_t)(bm + srow) * DM + sc * 8;
  const unsigned short* Ag2 = A + (size_t)(bm + srow + 64) * DM + sc * 8;
  const unsigned short* Bg1 = B + (size_t)(bn + srow) * DM + sc * 8;
  const unsigned short* Bg2 = B + (size_t)(bn + srow + 64) * DM + sc * 8;
  const int swz = (l16 >> 1) & 3;

  for (int k0 = 0; k0 < DM; k0 += 32) {
    __syncthreads();
    gld_lds16(Ag1 + k0, As + t * 8);
    gld_lds16(Ag2 + k0, As + t * 8 + 2048);
    gld_lds16(Bg1 + k0, Bs + t * 8);
    gld_lds16(Bg2 + k0, Bs + t * 8 + 2048);
    __syncthreads();
    short8 af[4], bfr[4];
#pragma unroll
    for (int i = 0; i < 4; ++i)
      af[i] = *(const short8*)(As + (wm + i * 16 + l16) * 32 + ((quad ^ swz) * 8));
#pragma unroll
    for (int j = 0; j < 4; ++j)
      bfr[j] = *(const short8*)(Bs + (wn + j * 16 + l16) * 32 + ((quad ^ swz) * 8));
#pragma unroll
    for (int i = 0; i < 4; ++i)
#pragma unroll
      for (int j = 0; j < 4; ++j)
        acc[i][j] = __builtin_amdgcn_mfma_f32_16x16x32_bf16(af[i], bfr[j], acc[i][j], 0, 0, 0);
  }

#pragma unroll
  for (int i = 0; i < 4; ++i)
#pragma unroll
    for (int j = 0; j < 4; ++j)
#pragma unroll
      for (int r = 0; r < 4; ++r) {
        const int m = bm + wm + i * 16 + quad * 4 + r;
        const int n = bn + wn + j * 16 + l16;
        C[(size_t)m * DM + n] = acc[i][j][r];
      }
}

// ---------------- causal flash attention, 128x128 tiles (round-8 proven structure) ----
// 2 blocks/CU co-resident (67.6 KB static LDS) hides staging latency via TLP
// (beat both 1-block/CU dbuf variants, R6/R9). XCD-grouped block mapping keeps
// each (b,h)'s 512 KB K/V L2-resident (FETCH 141->24.6 MB, R8 proven).
// R10 change: p = exp2f(s) — bare v_exp_f32 (log2e folded into Q pre-scale
// upstream), removing one v_mul per P element from the 48%-VALUBusy chain.
__global__ __launch_bounds__(512) void attn_kernel(const unsigned short* __restrict__ Q,
                                                   const unsigned short* __restrict__ K,
                                                   const unsigned short* __restrict__ Vt,
                                                   unsigned short* __restrict__ O) {
  __shared__ __align__(16) unsigned short Ks[128 * 64];     // [kseq][d]
  __shared__ __align__(16) unsigned short Vs[64 * 128];     // [d][kseq]
  __shared__ __align__(16) unsigned short Ps[8][16 * 136];  // [qr][kseq], stride 136
  const int t = threadIdx.x;
  const int lane = t & 63;
  const int wave = t >> 6;
  const int quad = lane >> 4;
  const int l16 = lane & 15;

  // XCD-grouped decode: lid -> g = (lid&7)*64 + (lid>>3); qt0 = g&7; (b,h) = g>>3.
  const int lid = blockIdx.x;                 // 0..511
  const int g = (lid & 7) * 64 + (lid >> 3);
  const int qt0 = g & 7;
  const int bh = g >> 3;                      // 0..63
  const int h = bh & 15;
  const int b = bh >> 4;

  const int ksr1 = t >> 3;
  const int ksr2 = (t + 512) >> 3;
  const int koff1 = (b * SEQ + ksr1) * DM + h * 64 + (((t & 7) ^ (ksr1 & 7)) * 8);
  const int koff2 = (b * SEQ + ksr2) * DM + h * 64 + (((t & 7) ^ (ksr2 & 7)) * 8);
  const int vsr1 = t >> 4;
  const int vsr2 = (t + 512) >> 4;
  const int voff1 = ((b * NH + h) * DH + vsr1) * SEQ + (((t & 15) ^ (vsr1 & 15)) * 8);
  const int voff2 = ((b * NH + h) * DH + vsr2) * SEQ + (((t & 15) ^ (vsr2 & 15)) * 8);
  unsigned short* Pw = &Ps[wave][0];
  const int swz = l16 & 7;

#pragma unroll 1
  for (int pass = 0; pass < 2; ++pass) {
    const int qt = (pass == 0) ? qt0 : 15 - qt0;
    const int qtile = qt * 128;
    const int row_lo = qtile + wave * 16;
    const int row_hi = row_lo + 15;

    const unsigned short* Qrow =
        Q + ((size_t)(b * SEQ + row_lo + l16)) * DM + h * 64;
    const short8 qf0 = *(const short8*)(Qrow + quad * 8);
    const short8 qf1 = *(const short8*)(Qrow + 32 + quad * 8);

    f32x4 o_acc[4];
#pragma unroll
    for (int nb = 0; nb < 4; ++nb) o_acc[nb] = {0.0f, 0.0f, 0.0f, 0.0f};
    float l_r[4] = {0.0f, 0.0f, 0.0f, 0.0f};

    const int ktiles = qt + 1;
    for (int kt = 0; kt < ktiles; ++kt) {
      const int kbase = kt * 128;
      __syncthreads();
      gld_lds16(K + koff1 + (size_t)kbase * DM, Ks + t * 8);
      gld_lds16(K + koff2 + (size_t)kbase * DM, Ks + (t + 512) * 8);
      gld_lds16(Vt + voff1 + kbase, Vs + t * 8);
      gld_lds16(Vt + voff2 + kbase, Vs + (t + 512) * 8);
      __syncthreads();

      if (kbase <= row_hi) {
        f32x4 s_acc[8];
#pragma unroll
        for (int nb = 0; nb < 8; ++nb) {
          s_acc[nb] = {0.0f, 0.0f, 0.0f, 0.0f};
          const short8 kf0 = *(const short8*)(Ks + (nb * 16 + l16) * 64 + ((quad ^ swz) * 8));
          const short8 kf1 = *(const short8*)(Ks + (nb * 16 + l16) * 64 + (((4 | quad) ^ swz) * 8));
          s_acc[nb] = __builtin_amdgcn_mfma_f32_16x16x32_bf16(qf0, kf0, s_acc[nb], 0, 0, 0);
          s_acc[nb] = __builtin_amdgcn_mfma_f32_16x16x32_bf16(qf1, kf1, s_acc[nb], 0, 0, 0);
        }

        const bool need_mask = (kbase + 127 > row_lo);
#pragma unroll
        for (int r = 0; r < 4; ++r) {
          const int qr = row_lo + quad * 4 + r;
#pragma unroll
          for (int nb = 0; nb < 8; ++nb) {
            float p = __builtin_exp2f(s_acc[nb][r]);  // 2^s = e^(s/log2e); scale folded
            if (need_mask) p = ((kbase + nb * 16 + l16) <= qr) ? p : 0.0f;
            l_r[r] += p;
            const unsigned u = __builtin_bit_cast(unsigned, p);
            Pw[(quad * 4 + r) * 136 + nb * 16 + l16] =
                (unsigned short)((u + 0x8000u) >> 16);
          }
        }

#pragma unroll
        for (int kk = 0; kk < 4; ++kk) {
          const short8 pf = *(const short8*)(Pw + l16 * 136 + kk * 32 + quad * 8);
#pragma unroll
          for (int nb = 0; nb < 4; ++nb) {
            const short8 vf = *(const short8*)(Vs + (nb * 16 + l16) * 128 +
                                               (((kk * 4 + quad) ^ l16) * 8));
            o_acc[nb] = __builtin_amdgcn_mfma_f32_16x16x32_bf16(pf, vf, o_acc[nb], 0, 0, 0);
          }
        }
      }
    }

#pragma unroll
    for (int r = 0; r < 4; ++r) {
      float ls = l_r[r];
      ls += __shfl_xor(ls, 1);
      ls += __shfl_xor(ls, 2);
      ls += __shfl_xor(ls, 4);
      ls += __shfl_xor(ls, 8);
      const float inv_l = 1.0f / ls;
      const int qr = row_lo + quad * 4 + r;
#pragma unroll
      for (int nb = 0; nb < 4; ++nb)
        O[((size_t)(b * SEQ + qr)) * DM + h * 64 + nb * 16 + l16] =
            f2bf(o_acc[nb][r] * inv_l);
    }
  }
}

extern "C" void kernel_launch(void* const* d_in, const int* in_sizes, int n_in,
                              void* d_out, int out_size, void* d_ws, size_t ws_size,
                              hipStream_t stream) {
  const float* x  = (const float*)d_in[0];
  const float* wq = (const float*)d_in[1];
  const float* wk = (const float*)d_in[2];
  const float* wv = (const float*)d_in[3];
  const float* wo = (const float*)d_in[4];

  char* ws = (char*)d_ws;
  unsigned short* xb    = (unsigned short*)(ws);              // 16 MiB
  unsigned short* wqkvb = (unsigned short*)(ws + 16777216);   // 6 MiB [3072,1024]
  unsigned short* wob   = (unsigned short*)(ws + 23068672);   // 2 MiB
  unsigned short* qb    = (unsigned short*)(ws + 25165824);   // 16 MiB (pre-scaled)
  unsigned short* kb    = (unsigned short*)(ws + 41943040);   // 16 MiB
  unsigned short* vtb   = (unsigned short*)(ws + 58720256);   // 16 MiB [B,NH,DH,SEQ]
  unsigned short* aob   = (unsigned short*)(ws + 75497472);   // 16 MiB

  static bool s_attr_done = false;
  if (!s_attr_done) {
    hipFuncSetAttribute(reinterpret_cast<const void*>(gemm_qkv256),
                        hipFuncAttributeMaxDynamicSharedMemorySize, 131072);
    s_attr_done = true;
  }

  cast_all_kernel<<<12288, 256, 0, stream>>>(x, wq, wk, wv, wo, xb, wqkvb, wob);

  gemm_qkv256<<<dim3(384), dim3(512), 131072, stream>>>(xb, wqkvb, qb, kb, vtb);

  attn_kernel<<<dim3(512), dim3(512), 0, stream>>>(qb, kb, vtb, aob);

  gemm_o<<<dim3(8, 64), 256, 0, stream>>>(aob, wob, (float*)d_out);
}

// Round 12
// 237.321 us; speedup vs baseline: 1.0662x; 1.0662x over previous
//
#include <hip/hip_runtime.h>
#include <cstdint>
#include <cstddef>

#define NH 16
#define DH 64
#define SEQ 2048
#define DM 1024

typedef __attribute__((ext_vector_type(8))) short short8;
typedef __attribute__((ext_vector_type(4))) float f32x4;

__device__ __forceinline__ unsigned short f2bf(float f) {
  unsigned u = __builtin_bit_cast(unsigned, f);
  u += 0x7fffu + ((u >> 16) & 1u);
  return (unsigned short)(u >> 16);
}

__device__ __forceinline__ void gld_lds16(const void* g, void* l) {
  __builtin_amdgcn_global_load_lds((const __attribute__((address_space(1))) void*)g,
                                   (__attribute__((address_space(3))) void*)l,
                                   16, 0, 0);
}

// ---------------- one-launch fp32 -> bf16 cast of x + all 4 weights ----------------
__global__ __launch_bounds__(256) void cast_all_kernel(const float* __restrict__ x,
                                                       const float* __restrict__ wq,
                                                       const float* __restrict__ wk,
                                                       const float* __restrict__ wv,
                                                       const float* __restrict__ wo,
                                                       unsigned short* __restrict__ xb,
                                                       unsigned short* __restrict__ wqkvb,
                                                       unsigned short* __restrict__ wob) {
  const int bid = blockIdx.x;
  const float* in;
  unsigned short* out;
  int i;
  if (bid < 8192) {
    in = x; out = xb; i = bid * 256 + threadIdx.x;
  } else {
    const int w = (bid - 8192) >> 10;
    i = ((bid - 8192) & 1023) * 256 + threadIdx.x;
    in = (w == 0) ? wq : (w == 1) ? wk : (w == 2) ? wv : wo;
    out = (w < 3) ? (wqkvb + (size_t)w * 1048576) : wob;
  }
  const float4 v = ((const float4*)in)[i];
  ushort4 o;
  o.x = f2bf(v.x); o.y = f2bf(v.y); o.z = f2bf(v.z); o.w = f2bf(v.w);
  ((ushort4*)out)[i] = o;
}

// ============ fused QKV GEMM: 256x256 tile, BK=64, 4-phase K-tiles (round-3 proven) ==
__global__ __launch_bounds__(512, 2) void gemm_qkv256(const unsigned short* __restrict__ A,
                                                      const unsigned short* __restrict__ W,
                                                      unsigned short* __restrict__ qb,
                                                      unsigned short* __restrict__ kb,
                                                      unsigned short* __restrict__ vtb) {
  extern __shared__ __align__(16) char sm[];   // [0,64K) = A par0/par1; [64K,128K) = B

  const int t = threadIdx.x;
  const int lane = t & 63;
  const int wave = t >> 6;            // 0..7
  const int quad = lane >> 4;
  const int l16 = lane & 15;
  const int wr = wave >> 2;           // 0,1  -> rows wr*128
  const int wc = wave & 3;            // 0..3 -> cols wc*64

  const int bid = blockIdx.x;         // 0..383
  const int xcd = bid & 7;
  const int idx = bid >> 3;           // 0..47
  const int bm = (xcd * 4 + idx / 12) * 256;
  const int bn = (idx % 12) * 256;
  const int sel = bn >> 10;
  const int bnl = bn & 1023;

  f32x4 acc[8][4];
#pragma unroll
  for (int i = 0; i < 8; ++i)
#pragma unroll
    for (int j = 0; j < 4; ++j) acc[i][j] = {0.0f, 0.0f, 0.0f, 0.0f};

  const int r0s = t >> 3;                         // 0..63
  const int g0 = (((t & 7) ^ (r0s & 7)) * 8);
  const unsigned short* aS0 = A + (size_t)(bm + r0s) * DM + g0;
  const unsigned short* aS1 = A + (size_t)(bm + 64 + r0s) * DM + g0;
  const unsigned short* bS0 = W + (size_t)(bn + r0s) * DM + g0;
  const unsigned short* bS1 = W + (size_t)(bn + 64 + r0s) * DM + g0;
  const int t16 = t * 16;

  const int aswz = (quad ^ (l16 & 7)) * 16;
  const int aRd0 = (wr * 128 + l16) * 128 + aswz;
  const int aRd1 = aRd0 ^ 64;
  const int bRd0 = 65536 + (wc * 64 + l16) * 128 + aswz;
  const int bRd1 = bRd0 ^ 64;

#define ST_A(U, TK, PAR)                                                                   \
  {                                                                                        \
    gld_lds16(aS0 + (size_t)(U) * 131072 + (TK) * 64, sm + (PAR) * 32768 + (U) * 16384 + t16); \
    gld_lds16(aS1 + (size_t)(U) * 131072 + (TK) * 64,                                      \
              sm + (PAR) * 32768 + (U) * 16384 + 8192 + t16);                              \
  }
#define ST_B(U, TK, PAR)                                                                   \
  {                                                                                        \
    gld_lds16(bS0 + (size_t)(U) * 131072 + (TK) * 64,                                      \
              sm + 65536 + (PAR) * 32768 + (U) * 16384 + t16);                             \
    gld_lds16(bS1 + (size_t)(U) * 131072 + (TK) * 64,                                      \
              sm + 65536 + (PAR) * 32768 + (U) * 16384 + 8192 + t16);                      \
  }

#define MM(AF, BF, IB, JB)                                                                 \
  _Pragma("unroll")                                                                        \
  for (int i = 0; i < 4; ++i)                                                              \
    _Pragma("unroll")                                                                      \
    for (int j = 0; j < 2; ++j) {                                                          \
      acc[(IB) + i][(JB) + j] = __builtin_amdgcn_mfma_f32_16x16x32_bf16(                   \
          AF[i][0], BF[j][0], acc[(IB) + i][(JB) + j], 0, 0, 0);                           \
      acc[(IB) + i][(JB) + j] = __builtin_amdgcn_mfma_f32_16x16x32_bf16(                   \
          AF[i][1], BF[j][1], acc[(IB) + i][(JB) + j], 0, 0, 0);                           \
    }

#define TILE(T, PAR, SB, SA, VM)                                                           \
  {                                                                                        \
    short8 af0[4][2], af1[4][2], bf0[2][2], bf1[2][2];                                     \
    _Pragma("unroll")                                                                      \
    for (int i = 0; i < 4; ++i) {                                                          \
      af0[i][0] = *(const short8*)(sm + (PAR) * 32768 + i * 2048 + aRd0);                  \
      af0[i][1] = *(const short8*)(sm + (PAR) * 32768 + i * 2048 + aRd1);                  \
    }                                                                                      \
    _Pragma("unroll")                                                                      \
    for (int j = 0; j < 2; ++j) {                                                          \
      bf0[j][0] = *(const short8*)(sm + (PAR) * 32768 + j * 2048 + bRd0);                  \
      bf0[j][1] = *(const short8*)(sm + (PAR) * 32768 + j * 2048 + bRd1);                  \
    }                                                                                      \
    if (SB) ST_B(0, (T) + 1, (PAR) ^ 1);                                                   \
    asm volatile("" ::: "memory");                                                         \
    __builtin_amdgcn_s_barrier();                                                          \
    asm volatile("s_waitcnt lgkmcnt(0)" ::: "memory");                                     \
    __builtin_amdgcn_s_setprio(1);                                                         \
    MM(af0, bf0, 0, 0);                                                                    \
    __builtin_amdgcn_s_setprio(0);                                                         \
    asm volatile("" ::: "memory");                                                         \
    __builtin_amdgcn_s_barrier();                                                          \
    _Pragma("unroll")                                                                      \
    for (int i = 0; i < 4; ++i) {                                                          \
      af1[i][0] = *(const short8*)(sm + (PAR) * 32768 + 8192 + i * 2048 + aRd0);           \
      af1[i][1] = *(const short8*)(sm + (PAR) * 32768 + 8192 + i * 2048 + aRd1);           \
    }                                                                                      \
    if (SB) ST_B(1, (T) + 1, (PAR) ^ 1);                                                   \
    asm volatile("" ::: "memory");                                                         \
    __builtin_amdgcn_s_barrier();                                                          \
    asm volatile("s_waitcnt lgkmcnt(0)" ::: "memory");                                     \
    __builtin_amdgcn_s_setprio(1);                                                         \
    MM(af1, bf0, 4, 0);                                                                    \
    __builtin_amdgcn_s_setprio(0);                                                         \
    asm volatile("" ::: "memory");                                                         \
    __builtin_amdgcn_s_barrier();                                                          \
    _Pragma("unroll")                                                                      \
    for (int j = 0; j < 2; ++j) {                                                          \
      bf1[j][0] = *(const short8*)(sm + (PAR) * 32768 + (2 + j) * 2048 + bRd0);            \
      bf1[j][1] = *(const short8*)(sm + (PAR) * 32768 + (2 + j) * 2048 + bRd1);            \
    }                                                                                      \
    if (SA) ST_A(0, (T) + 2, (PAR));                                                       \
    asm volatile("" ::: "memory");                                                         \
    __builtin_amdgcn_s_barrier();                                                          \
    asm volatile("s_waitcnt lgkmcnt(0)" ::: "memory");                                     \
    __builtin_amdgcn_s_setprio(1);                                                         \
    MM(af1, bf1, 4, 2);                                                                    \
    __builtin_amdgcn_s_setprio(0);                                                         \
    asm volatile("" ::: "memory");                                                         \
    __builtin_amdgcn_s_barrier();                                                          \
    if (SA) ST_A(1, (T) + 2, (PAR));                                                       \
    asm volatile("" ::: "memory");                                                         \
    __builtin_amdgcn_s_barrier();                                                          \
    __builtin_amdgcn_s_setprio(1);                                                         \
    MM(af0, bf1, 0, 2);                                                                    \
    __builtin_amdgcn_s_setprio(0);                                                         \
    if ((VM) == 4) asm volatile("s_waitcnt vmcnt(4)" ::: "memory");                        \
    else if ((VM) == 0) asm volatile("s_waitcnt vmcnt(0)" ::: "memory");                   \
    asm volatile("" ::: "memory");                                                         \
    __builtin_amdgcn_s_barrier();                                                          \
  }

  ST_A(0, 0, 0); ST_A(1, 0, 0);
  ST_B(0, 0, 0); ST_B(1, 0, 0);
  ST_A(0, 1, 1); ST_A(1, 1, 1);
  asm volatile("s_waitcnt vmcnt(4)" ::: "memory");
  __builtin_amdgcn_s_barrier();

#pragma unroll 1
  for (int tp = 0; tp < 7; ++tp) {      // tiles 0..13
    const int T0 = tp * 2;
    TILE(T0, 0, 1, 1, 4)
    TILE(T0 + 1, 1, 1, 1, 4)
  }
  TILE(14, 0, 1, 0, 0)
  TILE(15, 1, 0, 0, -1)

#undef TILE
#undef MM
#undef ST_A
#undef ST_B

  if (sel == 2) {
    // ---- V epilogue: LDS transpose -> coalesced dwordx4 stores along s ----
    __syncthreads();
#pragma unroll
    for (int i = 0; i < 8; ++i) {
#pragma unroll
      for (int j = 0; j < 4; ++j) {
        const int n = wc * 64 + j * 16 + l16;
        const int nrow = n * 512;
        const int cswz = (n & 15) << 5;
        const int mb = wr * 128 + i * 16 + quad * 4;
#pragma unroll
        for (int rp = 0; rp < 2; ++rp) {
          const unsigned lo = f2bf(acc[i][j][rp * 2]);
          const unsigned hi = f2bf(acc[i][j][rp * 2 + 1]);
          const int m0 = mb + rp * 2;
          *(unsigned*)(sm + nrow + ((2 * m0) ^ cswz)) = lo | (hi << 16);
        }
      }
    }
    __syncthreads();
    const int mc = t & 31;
    const int nb0 = t >> 5;
    const int bb = bm >> 11;
    const int sbase = (bm & 2047) + mc * 8;
#pragma unroll
    for (int c = 0; c < 16; ++c) {
      const int n = nb0 + c * 16;
      const f32x4 v = *(const f32x4*)(sm + n * 512 + ((mc * 16) ^ ((n & 15) << 5)));
      const int gcol = bnl + n;
      const int h = gcol >> 6, d = gcol & 63;
      *(f32x4*)(vtb + ((size_t)((bb * NH + h) * DH + d)) * SEQ + sbase) = v;
    }
  } else {
#pragma unroll
    for (int i = 0; i < 8; ++i) {
#pragma unroll
      for (int j = 0; j < 4; ++j) {
#pragma unroll
        for (int r = 0; r < 4; ++r) {
          const int m = bm + wr * 128 + i * 16 + quad * 4 + r;
          const int n = bnl + wc * 64 + j * 16 + l16;
          const float v = acc[i][j][r];
          if (sel == 0) {
            // q pre-scaled by 1/sqrt(Dh) = 0.125 (EXACT power-of-2). The exp line
            // (log2e fold) is CLOSED: R7 asm=hazard-fail, R10 builtin=denorm-slow,
            // R11 amdgcn-builtin=post-timing divergence. __expf is the proven path.
            qb[(size_t)m * DM + n] = f2bf(v * 0.125f);
          } else {
            kb[(size_t)m * DM + n] = f2bf(v);
          }
        }
      }
    }
  }
}

// ============ O-projection GEMM, BK=32: fp32 out, XCD-aware remap (round-3) ========
__global__ __launch_bounds__(256, 4) void gemm_o(const unsigned short* __restrict__ A,
                                                 const unsigned short* __restrict__ B,
                                                 float* __restrict__ C) {
  __shared__ __align__(16) unsigned short As[128 * 32];
  __shared__ __align__(16) unsigned short Bs[128 * 32];
  const int t = threadIdx.x;
  const int lane = t & 63;
  const int wave = t >> 6;
  const int quad = lane >> 4;
  const int l16 = lane & 15;
  const int wm = (wave >> 1) * 64;
  const int wn = (wave & 1) * 64;

  const int lid = blockIdx.x + 8 * blockIdx.y;   // 0..511
  const int xcd = lid & 7;
  const int idx = lid >> 3;                      // 0..63
  const int bm = (xcd * 8 + idx / 8) * 128;
  const int bn = (idx % 8) * 128;

  f32x4 acc[4][4];
#pragma unroll
  for (int i = 0; i < 4; ++i)
#pragma unroll
    for (int j = 0; j < 4; ++j) acc[i][j] = {0.0f, 0.0f, 0.0f, 0.0f};

  const int srow = t >> 2;
  const int sc = (t & 3) ^ ((srow >> 1) & 3);
  const unsigned short* Ag1 = A + (size_t)(bm + srow) * DM + sc * 8;
  const unsigned short* Ag2 = A + (size_t)(bm + srow + 64) * DM + sc * 8;
  const unsigned short* Bg1 = B + (size_t)(bn + srow) * DM + sc * 8;
  const unsigned short* Bg2 = B + (size_t)(bn + srow + 64) * DM + sc * 8;
  const int swz = (l16 >> 1) & 3;

  for (int k0 = 0; k0 < DM; k0 += 32) {
    __syncthreads();
    gld_lds16(Ag1 + k0, As + t * 8);
    gld_lds16(Ag2 + k0, As + t * 8 + 2048);
    gld_lds16(Bg1 + k0, Bs + t * 8);
    gld_lds16(Bg2 + k0, Bs + t * 8 + 2048);
    __syncthreads();
    short8 af[4], bfr[4];
#pragma unroll
    for (int i = 0; i < 4; ++i)
      af[i] = *(const short8*)(As + (wm + i * 16 + l16) * 32 + ((quad ^ swz) * 8));
#pragma unroll
    for (int j = 0; j < 4; ++j)
      bfr[j] = *(const short8*)(Bs + (wn + j * 16 + l16) * 32 + ((quad ^ swz) * 8));
#pragma unroll
    for (int i = 0; i < 4; ++i)
#pragma unroll
      for (int j = 0; j < 4; ++j)
        acc[i][j] = __builtin_amdgcn_mfma_f32_16x16x32_bf16(af[i], bfr[j], acc[i][j], 0, 0, 0);
  }

#pragma unroll
  for (int i = 0; i < 4; ++i)
#pragma unroll
    for (int j = 0; j < 4; ++j)
#pragma unroll
      for (int r = 0; r < 4; ++r) {
        const int m = bm + wm + i * 16 + quad * 4 + r;
        const int n = bn + wn + j * 16 + l16;
        C[(size_t)m * DM + n] = acc[i][j][r];
      }
}

// ---------------- causal flash attention, 128x128 tiles (round-8 proven structure) ----
// Numerics identical to round 3 (q pre-scaled 0.125, __expf). 2 blocks/CU
// co-resident (67.6 KB static LDS) hides staging latency via TLP. XCD-grouped
// block mapping keeps each (b,h)'s 512 KB K/V L2-resident (FETCH 141->24.6 MB).
__global__ __launch_bounds__(512) void attn_kernel(const unsigned short* __restrict__ Q,
                                                   const unsigned short* __restrict__ K,
                                                   const unsigned short* __restrict__ Vt,
                                                   unsigned short* __restrict__ O) {
  __shared__ __align__(16) unsigned short Ks[128 * 64];     // [kseq][d]
  __shared__ __align__(16) unsigned short Vs[64 * 128];     // [d][kseq]
  __shared__ __align__(16) unsigned short Ps[8][16 * 136];  // [qr][kseq], stride 136
  const int t = threadIdx.x;
  const int lane = t & 63;
  const int wave = t >> 6;
  const int quad = lane >> 4;
  const int l16 = lane & 15;

  // XCD-grouped decode: lid -> g = (lid&7)*64 + (lid>>3); qt0 = g&7; (b,h) = g>>3.
  const int lid = blockIdx.x;                 // 0..511
  const int g = (lid & 7) * 64 + (lid >> 3);
  const int qt0 = g & 7;
  const int bh = g >> 3;                      // 0..63
  const int h = bh & 15;
  const int b = bh >> 4;

  const int ksr1 = t >> 3;
  const int ksr2 = (t + 512) >> 3;
  const int koff1 = (b * SEQ + ksr1) * DM + h * 64 + (((t & 7) ^ (ksr1 & 7)) * 8);
  const int koff2 = (b * SEQ + ksr2) * DM + h * 64 + (((t & 7) ^ (ksr2 & 7)) * 8);
  const int vsr1 = t >> 4;
  const int vsr2 = (t + 512) >> 4;
  const int voff1 = ((b * NH + h) * DH + vsr1) * SEQ + (((t & 15) ^ (vsr1 & 15)) * 8);
  const int voff2 = ((b * NH + h) * DH + vsr2) * SEQ + (((t & 15) ^ (vsr2 & 15)) * 8);
  unsigned short* Pw = &Ps[wave][0];
  const int swz = l16 & 7;

#pragma unroll 1
  for (int pass = 0; pass < 2; ++pass) {
    const int qt = (pass == 0) ? qt0 : 15 - qt0;
    const int qtile = qt * 128;
    const int row_lo = qtile + wave * 16;
    const int row_hi = row_lo + 15;

    const unsigned short* Qrow =
        Q + ((size_t)(b * SEQ + row_lo + l16)) * DM + h * 64;
    const short8 qf0 = *(const short8*)(Qrow + quad * 8);
    const short8 qf1 = *(const short8*)(Qrow + 32 + quad * 8);

    f32x4 o_acc[4];
#pragma unroll
    for (int nb = 0; nb < 4; ++nb) o_acc[nb] = {0.0f, 0.0f, 0.0f, 0.0f};
    float l_r[4] = {0.0f, 0.0f, 0.0f, 0.0f};

    const int ktiles = qt + 1;
    for (int kt = 0; kt < ktiles; ++kt) {
      const int kbase = kt * 128;
      __syncthreads();
      gld_lds16(K + koff1 + (size_t)kbase * DM, Ks + t * 8);
      gld_lds16(K + koff2 + (size_t)kbase * DM, Ks + (t + 512) * 8);
      gld_lds16(Vt + voff1 + kbase, Vs + t * 8);
      gld_lds16(Vt + voff2 + kbase, Vs + (t + 512) * 8);
      __syncthreads();

      if (kbase <= row_hi) {
        f32x4 s_acc[8];
#pragma unroll
        for (int nb = 0; nb < 8; ++nb) {
          s_acc[nb] = {0.0f, 0.0f, 0.0f, 0.0f};
          const short8 kf0 = *(const short8*)(Ks + (nb * 16 + l16) * 64 + ((quad ^ swz) * 8));
          const short8 kf1 = *(const short8*)(Ks + (nb * 16 + l16) * 64 + (((4 | quad) ^ swz) * 8));
          s_acc[nb] = __builtin_amdgcn_mfma_f32_16x16x32_bf16(qf0, kf0, s_acc[nb], 0, 0, 0);
          s_acc[nb] = __builtin_amdgcn_mfma_f32_16x16x32_bf16(qf1, kf1, s_acc[nb], 0, 0, 0);
        }

        const bool need_mask = (kbase + 127 > row_lo);
#pragma unroll
        for (int r = 0; r < 4; ++r) {
          const int qr = row_lo + quad * 4 + r;
#pragma unroll
          for (int nb = 0; nb < 8; ++nb) {
            float p = __expf(s_acc[nb][r]);
            if (need_mask) p = ((kbase + nb * 16 + l16) <= qr) ? p : 0.0f;
            l_r[r] += p;
            const unsigned u = __builtin_bit_cast(unsigned, p);
            Pw[(quad * 4 + r) * 136 + nb * 16 + l16] =
                (unsigned short)((u + 0x8000u) >> 16);
          }
        }

#pragma unroll
        for (int kk = 0; kk < 4; ++kk) {
          const short8 pf = *(const short8*)(Pw + l16 * 136 + kk * 32 + quad * 8);
#pragma unroll
          for (int nb = 0; nb < 4; ++nb) {
            const short8 vf = *(const short8*)(Vs + (nb * 16 + l16) * 128 +
                                               (((kk * 4 + quad) ^ l16) * 8));
            o_acc[nb] = __builtin_amdgcn_mfma_f32_16x16x32_bf16(pf, vf, o_acc[nb], 0, 0, 0);
          }
        }
      }
    }

#pragma unroll
    for (int r = 0; r < 4; ++r) {
      float ls = l_r[r];
      ls += __shfl_xor(ls, 1);
      ls += __shfl_xor(ls, 2);
      ls += __shfl_xor(ls, 4);
      ls += __shfl_xor(ls, 8);
      const float inv_l = 1.0f / ls;
      const int qr = row_lo + quad * 4 + r;
#pragma unroll
      for (int nb = 0; nb < 4; ++nb)
        O[((size_t)(b * SEQ + qr)) * DM + h * 64 + nb * 16 + l16] =
            f2bf(o_acc[nb][r] * inv_l);
    }
  }
}

extern "C" void kernel_launch(void* const* d_in, const int* in_sizes, int n_in,
                              void* d_out, int out_size, void* d_ws, size_t ws_size,
                              hipStream_t stream) {
  const float* x  = (const float*)d_in[0];
  const float* wq = (const float*)d_in[1];
  const float* wk = (const float*)d_in[2];
  const float* wv = (const float*)d_in[3];
  const float* wo = (const float*)d_in[4];

  char* ws = (char*)d_ws;
  unsigned short* xb    = (unsigned short*)(ws);              // 16 MiB
  unsigned short* wqkvb = (unsigned short*)(ws + 16777216);   // 6 MiB [3072,1024]
  unsigned short* wob   = (unsigned short*)(ws + 23068672);   // 2 MiB
  unsigned short* qb    = (unsigned short*)(ws + 25165824);   // 16 MiB (pre-scaled)
  unsigned short* kb    = (unsigned short*)(ws + 41943040);   // 16 MiB
  unsigned short* vtb   = (unsigned short*)(ws + 58720256);   // 16 MiB [B,NH,DH,SEQ]
  unsigned short* aob   = (unsigned short*)(ws + 75497472);   // 16 MiB

  static bool s_attr_done = false;
  if (!s_attr_done) {
    hipFuncSetAttribute(reinterpret_cast<const void*>(gemm_qkv256),
                        hipFuncAttributeMaxDynamicSharedMemorySize, 131072);
    s_attr_done = true;
  }

  cast_all_kernel<<<12288, 256, 0, stream>>>(x, wq, wk, wv, wo, xb, wqkvb, wob);

  gemm_qkv256<<<dim3(384), dim3(512), 131072, stream>>>(xb, wqkvb, qb, kb, vtb);

  attn_kernel<<<dim3(512), dim3(512), 0, stream>>>(qb, kb, vtb, aob);

  gemm_o<<<dim3(8, 64), 256, 0, stream>>>(aob, wob, (float*)d_out);
}